// Round 6
// baseline (304.986 us; speedup 1.0000x reference)
//
#include <hip/hip_runtime.h>
#include <math.h>

#define CH 512
#define RED 64

typedef __attribute__((ext_vector_type(4))) float f32x4;
typedef long i64;

typedef const __attribute__((address_space(1))) void* gas_t;
typedef __attribute__((address_space(3))) void* las_t;

static __device__ __forceinline__ void gl16(const void* g, void* l) {
    __builtin_amdgcn_global_load_lds((gas_t)g, (las_t)l, 16, 0, 0);
}

// pack 4 f32 -> 4 fp8 e4m3 bytes
static __device__ __forceinline__ unsigned pk4(float a, float b, float c, float d) {
    int w = __builtin_amdgcn_cvt_pk_fp8_f32(a, b, 0, false);
    w = __builtin_amdgcn_cvt_pk_fp8_f32(c, d, w, true);
    return (unsigned)w;
}
static __device__ __forceinline__ unsigned char pk1(float a) {
    return (unsigned char)(__builtin_amdgcn_cvt_pk_fp8_f32(a, a, 0, false) & 0xFF);
}

// ---------------------------------------------------------------------------
// prep_w: Wq|Wk|Wv f32 -> Wcat fp8 [640][512]; rows 0-63 q, 64-127 k, 128-639 v.
// ---------------------------------------------------------------------------
__global__ __launch_bounds__(128) void prep_w(
    const float* __restrict__ Wq, const float* __restrict__ Wk,
    const float* __restrict__ Wv, unsigned char* __restrict__ Wcat)
{
    const int r = blockIdx.x, t = threadIdx.x;
    const float* src = (r < 64) ? (Wq + (size_t)r * CH)
                     : (r < 128) ? (Wk + (size_t)(r - 64) * CH)
                                 : (Wv + (size_t)(r - 128) * CH);
    const float4 v = *(const float4*)&src[t * 4];
    *(unsigned*)&Wcat[(size_t)r * CH + t * 4] = pk4(v.x, v.y, v.z, v.w);
}

// ---------------------------------------------------------------------------
// cast_xt: x f32 [b][c][n] -> xT fp8 [b][n][512].  64x64 tiles.
// ---------------------------------------------------------------------------
__global__ __launch_bounds__(256) void cast_xt(
    const float* __restrict__ x, unsigned char* __restrict__ xT, int n)
{
    __shared__ float sX[64][65];
    const int b = blockIdx.z, i0 = blockIdx.x * 64, c0 = blockIdx.y * 64;
    const int t = threadIdx.x;
    #pragma unroll
    for (int s = 0; s < 4; ++s) {
        const int id = s * 256 + t, c = id >> 4, seg = id & 15;
        *(float4*)&sX[c][seg * 4] = *(const float4*)&x[((size_t)b * CH + c0 + c) * n + i0 + seg * 4];
    }
    __syncthreads();
    const int i = t >> 2, cp = t & 3;
    uint4 w;
    w.x = pk4(sX[cp*16+ 0][i], sX[cp*16+ 1][i], sX[cp*16+ 2][i], sX[cp*16+ 3][i]);
    w.y = pk4(sX[cp*16+ 4][i], sX[cp*16+ 5][i], sX[cp*16+ 6][i], sX[cp*16+ 7][i]);
    w.z = pk4(sX[cp*16+ 8][i], sX[cp*16+ 9][i], sX[cp*16+10][i], sX[cp*16+11][i]);
    w.w = pk4(sX[cp*16+12][i], sX[cp*16+13][i], sX[cp*16+14][i], sX[cp*16+15][i]);
    *(uint4*)&xT[((size_t)b * n + i0 + i) * CH + c0 + cp * 16] = w;
}

// ---------------------------------------------------------------------------
// qkv_gemm (fp8): out = xT * Wcat^T + bias.  128i x 128o tiles, K=512.
// o-block 0 -> q[b][n][64] + k[b][n][64]; o-blocks 1..4 -> v2[b][c][n] (transposed).
// Rows staged as 5x16B chunks (80 B stride; 5th chunk dups chunk 0 for the
// linear lane->LDS mapping global_load_lds requires).
// ---------------------------------------------------------------------------
__global__ __launch_bounds__(256, 4) void qkv_gemm(
    const unsigned char* __restrict__ xT, const unsigned char* __restrict__ Wcat,
    const float* __restrict__ bq, const float* __restrict__ bk,
    const float* __restrict__ bv,
    unsigned char* __restrict__ qF, unsigned char* __restrict__ kF,
    unsigned char* __restrict__ v2, int n)
{
    __shared__ char smem[20480];   // sA 128x80 | sB 128x80
    const int b = blockIdx.z, i0 = blockIdx.x * 128, o0 = blockIdx.y * 128;
    const int t = threadIdx.x, lane = t & 63;
    const int quad = lane >> 4, l16 = lane & 15;
    const int wrow = (t >> 6) & 1, wcol = t >> 7;

    f32x4 acc[4][4];
    const f32x4 zz = {0.f, 0.f, 0.f, 0.f};
    #pragma unroll
    for (int mi = 0; mi < 4; ++mi)
        #pragma unroll
        for (int ci = 0; ci < 4; ++ci) acc[mi][ci] = zz;

    const unsigned char* Ab = xT + ((size_t)b * n + i0) * CH;
    const unsigned char* Bb = Wcat + (size_t)o0 * CH;

    for (int c0 = 0; c0 < CH; c0 += 64) {
        #pragma unroll
        for (int s = 0; s < 5; ++s) {
            const int c = s * 256 + t;           // 1280 chunks: A 0..639, B 640..1279
            const bool isA = c < 640;
            const int tc = isA ? c : c - 640;
            const int r = tc / 5, p = (tc % 5) & 3;
            gl16((isA ? Ab : Bb) + (size_t)r * CH + c0 + p * 16,
                 smem + (isA ? 0 : 10240) + (size_t)tc * 16);
        }
        __syncthreads();
        #pragma unroll
        for (int kk = 0; kk < 64; kk += 32) {
            i64 af[4], bf[4];
            #pragma unroll
            for (int mi = 0; mi < 4; ++mi)
                af[mi] = *(const i64*)(smem + (wrow * 64 + mi * 16 + l16) * 80 + kk + quad * 8);
            #pragma unroll
            for (int ci = 0; ci < 4; ++ci)
                bf[ci] = *(const i64*)(smem + 10240 + (wcol * 64 + ci * 16 + l16) * 80 + kk + quad * 8);
            #pragma unroll
            for (int mi = 0; mi < 4; ++mi)
                #pragma unroll
                for (int ci = 0; ci < 4; ++ci)
                    acc[mi][ci] = __builtin_amdgcn_mfma_f32_16x16x32_fp8_fp8(af[mi], bf[ci], acc[mi][ci], 0, 0, 0);
        }
        __syncthreads();
    }

    // bias per lane per ci
    float bb[4];
    #pragma unroll
    for (int ci = 0; ci < 4; ++ci) {
        const int o = wcol * 64 + ci * 16 + l16;
        bb[ci] = (o0 == 0) ? ((o < 64) ? bq[o] : bk[o - 64]) : bv[o0 - 128 + o];
    }
    __syncthreads();
    unsigned char* sE = (unsigned char*)smem;    // 128 x 144
    if (o0 == 0) {
        #pragma unroll
        for (int mi = 0; mi < 4; ++mi)
            #pragma unroll
            for (int ci = 0; ci < 4; ++ci)
                #pragma unroll
                for (int r = 0; r < 4; ++r)
                    sE[(wrow*64 + mi*16 + quad*4 + r) * 144 + wcol*64 + ci*16 + l16] =
                        pk1(acc[mi][ci][r] + bb[ci]);
    } else {
        #pragma unroll
        for (int mi = 0; mi < 4; ++mi)
            #pragma unroll
            for (int ci = 0; ci < 4; ++ci)
                #pragma unroll
                for (int r = 0; r < 4; ++r)
                    sE[(wcol*64 + ci*16 + l16) * 144 + wrow*64 + mi*16 + quad*4 + r] =
                        pk1(acc[mi][ci][r] + bb[ci]);
    }
    __syncthreads();
    if (o0 == 0) {
        #pragma unroll
        for (int u = 0; u < 2; ++u) {
            const int id = u * 256 + t, i = id >> 2, p = id & 3;
            *(uint4*)&qF[((size_t)b * n + i0 + i) * RED + p * 16] = *(const uint4*)&sE[i * 144 + p * 16];
        }
        #pragma unroll
        for (int u = 0; u < 2; ++u) {
            const int id = u * 256 + t, i = id >> 2, p = id & 3;
            *(uint4*)&kF[((size_t)b * n + i0 + i) * RED + p * 16] = *(const uint4*)&sE[i * 144 + 64 + p * 16];
        }
    } else {
        #pragma unroll
        for (int u = 0; u < 4; ++u) {
            const int id = u * 256 + t, o = id >> 3, p = id & 7;
            *(uint4*)&v2[((size_t)b * CH + (o0 - 128) + o) * n + i0 + p * 16] =
                *(const uint4*)&sE[o * 144 + p * 16];
        }
    }
}

// ---------------------------------------------------------------------------
// rowmax: m_i = max_j S (S = q.k^T via the SAME fp8 MFMA sequence the attn
// kernel uses -> bit-identical S).  128x128 tiles, atomicMax with monotone
// unsigned float encoding (mKey pre-zeroed).
// ---------------------------------------------------------------------------
__global__ __launch_bounds__(256, 4) void rowmax(
    const unsigned char* __restrict__ qF, const unsigned char* __restrict__ kF,
    unsigned* __restrict__ mKey, int n)
{
    __shared__ char smem[20480];   // sQ 128x80 | sK 128x80
    const int b = blockIdx.z, i0 = blockIdx.y * 128, j0 = blockIdx.x * 128;
    const int t = threadIdx.x, lane = t & 63;
    const int quad = lane >> 4, l16 = lane & 15;
    const int wrow = (t >> 6) & 1, wcol = t >> 7;

    const unsigned char* Qb = qF + ((size_t)b * n + i0) * RED;
    const unsigned char* Kb = kF + ((size_t)b * n + j0) * RED;
    #pragma unroll
    for (int s = 0; s < 5; ++s) {
        const int c = s * 256 + t;           // 1280: Q 0..639, K 640..1279
        const bool isQ = c < 640;
        const int tc = isQ ? c : c - 640;
        const int r = tc / 5, p = (tc % 5) & 3;
        gl16((isQ ? Qb : Kb) + (size_t)r * RED + p * 16,
             smem + (isQ ? 0 : 10240) + (size_t)tc * 16);
    }
    __syncthreads();

    f32x4 acc[4][4];
    const f32x4 zz = {0.f, 0.f, 0.f, 0.f};
    #pragma unroll
    for (int mi = 0; mi < 4; ++mi)
        #pragma unroll
        for (int ci = 0; ci < 4; ++ci) acc[mi][ci] = zz;

    #pragma unroll
    for (int kk = 0; kk < 64; kk += 32) {
        i64 af[4], bf[4];
        #pragma unroll
        for (int mi = 0; mi < 4; ++mi)
            af[mi] = *(const i64*)(smem + (wrow * 64 + mi * 16 + l16) * 80 + kk + quad * 8);
        #pragma unroll
        for (int ci = 0; ci < 4; ++ci)
            bf[ci] = *(const i64*)(smem + 10240 + (wcol * 64 + ci * 16 + l16) * 80 + kk + quad * 8);
        #pragma unroll
        for (int mi = 0; mi < 4; ++mi)
            #pragma unroll
            for (int ci = 0; ci < 4; ++ci)
                acc[mi][ci] = __builtin_amdgcn_mfma_f32_16x16x32_fp8_fp8(af[mi], bf[ci], acc[mi][ci], 0, 0, 0);
    }

    #pragma unroll
    for (int mi = 0; mi < 4; ++mi)
        #pragma unroll
        for (int r = 0; r < 4; ++r) {
            float mx = fmaxf(fmaxf(acc[mi][0][r], acc[mi][1][r]),
                             fmaxf(acc[mi][2][r], acc[mi][3][r]));
            #pragma unroll
            for (int off = 1; off < 16; off <<= 1) mx = fmaxf(mx, __shfl_xor(mx, off));
            if (l16 == 0) {
                union { float f; unsigned u; } cv; cv.f = mx;
                const unsigned key = ((int)cv.u >= 0) ? (cv.u + 0x80000000u) : ~cv.u;
                atomicMax(&mKey[(size_t)b * n + i0 + wrow * 64 + mi * 16 + quad * 4 + r], key);
            }
        }
}

// ---------------------------------------------------------------------------
// attn: fused S -> P=exp(S-m) fp8 -> O += P V^T, all fp8 MFMA.
// Block: 128 q x 128 ch, 1024 thr (16 waves), 35.8 KB LDS -> 2 blocks/CU.
// Grid (16,32): x = combo (b*4 + chgrp) so each XCD's round-robin share
// sees 2 combos -> K/V working set ~1.5 MB, L2-resident.
// wave w: mi = w&7 (16-row i-strip), cg = w>>3 (j-half for S, 64-ch half for PV).
// ---------------------------------------------------------------------------
__global__ __launch_bounds__(1024, 8) void attn(
    const unsigned char* __restrict__ qF,   // [b][n][64] fp8
    const unsigned char* __restrict__ kF,   // [b][n][64] fp8
    const unsigned char* __restrict__ v2,   // [b][512][n] fp8
    const unsigned* __restrict__ mKey,
    const float* __restrict__ x, const float* __restrict__ gamma,
    float* __restrict__ y, int n)
{
    __shared__ char smem[35840];
    // sQ 0 (128x80) | sK 10240 (64x80) | sP 15360 (128x80) | sV 25600 (128x80)
    const int combo = blockIdx.x, it = blockIdx.y;
    const int b = combo >> 2, ch0 = (combo & 3) * 128;
    const int i0 = it * 128;
    const int t = threadIdx.x, lane = t & 63, w = t >> 6;
    const int quad = lane >> 4, l16 = lane & 15;
    const int mi = w & 7, cg = w >> 3;

    // stage Q once: 640 chunks
    {
        const unsigned char* Qb = qF + ((size_t)b * n + i0) * RED;
        if (t < 640) {
            const int r = t / 5, p = (t % 5) & 3;
            gl16(Qb + (size_t)r * RED + p * 16, smem + (size_t)t * 16);
        }
    }
    // row max for this wave's rows (exact: same fp8 S computation as rowmax)
    float mrow[4];
    #pragma unroll
    for (int r = 0; r < 4; ++r) {
        const unsigned u = mKey[(size_t)b * n + i0 + mi * 16 + quad * 4 + r];
        const unsigned bits = (u >= 0x80000000u) ? (u - 0x80000000u) : ~u;
        union { unsigned u; float f; } cv; cv.u = bits;
        mrow[r] = cv.f;
    }

    f32x4 acc[4];
    const f32x4 zz = {0.f, 0.f, 0.f, 0.f};
    #pragma unroll
    for (int ct = 0; ct < 4; ++ct) acc[ct] = zz;
    float lacc[4] = {0.f, 0.f, 0.f, 0.f};

    const unsigned char* Kb = kF + (size_t)b * n * RED;
    const unsigned char* Vb = v2 + ((size_t)b * CH + ch0) * n;

    __syncthreads();   // Q staged (vmcnt drain at barrier)
    const i64 aq0 = *(const i64*)(smem + (mi * 16 + l16) * 80 + 0 + quad * 8);
    const i64 aq1 = *(const i64*)(smem + (mi * 16 + l16) * 80 + 32 + quad * 8);

    for (int j0 = 0; j0 < n; j0 += 64) {
        __syncthreads();   // prior chunk's sK/sV/sP reads done
        if (t < 960) {     // K 0..319 (64x5), V 320..959 (128x5)
            const bool isK = t < 320;
            const int tc = isK ? t : t - 320;
            const int r = tc / 5, p = (tc % 5) & 3;
            if (isK) gl16(Kb + (size_t)(j0 + r) * RED + p * 16, smem + 10240 + (size_t)tc * 16);
            else     gl16(Vb + (size_t)r * n + j0 + p * 16,    smem + 25600 + (size_t)tc * 16);
        }
        __syncthreads();   // staging drained

        // S for this wave's 16 x 32 piece (2 j-tiles), P = exp(S-m) -> fp8 LDS
        #pragma unroll
        for (int u = 0; u < 2; ++u) {
            f32x4 S = zz;
            const i64 bk0 = *(const i64*)(smem + 10240 + (cg * 32 + u * 16 + l16) * 80 + 0 + quad * 8);
            S = __builtin_amdgcn_mfma_f32_16x16x32_fp8_fp8(aq0, bk0, S, 0, 0, 0);
            const i64 bk1 = *(const i64*)(smem + 10240 + (cg * 32 + u * 16 + l16) * 80 + 32 + quad * 8);
            S = __builtin_amdgcn_mfma_f32_16x16x32_fp8_fp8(aq1, bk1, S, 0, 0, 0);
            #pragma unroll
            for (int r = 0; r < 4; ++r) {
                const float e = __expf(S[r] - mrow[r]);
                lacc[r] += e;
                smem[15360 + (mi * 16 + quad * 4 + r) * 80 + cg * 32 + u * 16 + l16] = pk1(e);
            }
        }
        __syncthreads();   // P visible

        // PV: rows mi*16, channels cg*64 (4 tiles)
        #pragma unroll
        for (int kk = 0; kk < 64; kk += 32) {
            const i64 af = *(const i64*)(smem + 15360 + (mi * 16 + l16) * 80 + kk + quad * 8);
            #pragma unroll
            for (int ct = 0; ct < 4; ++ct) {
                const i64 bf = *(const i64*)(smem + 25600 + (cg * 64 + ct * 16 + l16) * 80 + kk + quad * 8);
                acc[ct] = __builtin_amdgcn_mfma_f32_16x16x32_fp8_fp8(af, bf, acc[ct], 0, 0, 0);
            }
        }
    }

    // l reduce: shfl over 16 lanes, combine the two cg groups via LDS
    float* sL = (float*)(smem + 10240);   // [2][128]
    __syncthreads();
    #pragma unroll
    for (int r = 0; r < 4; ++r) {
        float v = lacc[r];
        #pragma unroll
        for (int off = 1; off < 16; off <<= 1) v += __shfl_xor(v, off);
        if (l16 == 0) sL[cg * 128 + mi * 16 + quad * 4 + r] = v;
    }
    __syncthreads();
    float il[4];
    #pragma unroll
    for (int r = 0; r < 4; ++r) {
        const int row = mi * 16 + quad * 4 + r;
        il[r] = 1.0f / (sL[row] + sL[128 + row]);
    }

    // Epilogue: y = g*(O/l) + x; transpose 64-ch halves through LDS
    const float g = gamma[0];
    float* sT = (float*)smem;   // [64][132]
    #pragma unroll
    for (int h = 0; h < 2; ++h) {
        __syncthreads();
        if (cg == h) {
            #pragma unroll
            for (int ct = 0; ct < 4; ++ct)
                #pragma unroll
                for (int r = 0; r < 4; ++r)
                    sT[(ct * 16 + l16) * 132 + mi * 16 + quad * 4 + r] = acc[ct][r] * il[r];
        }
        __syncthreads();
        #pragma unroll
        for (int u = 0; u < 2; ++u) {
            const int id = u * 1024 + t, c = id >> 5, seg = id & 31;
            const size_t gb = ((size_t)b * CH + ch0 + h * 64 + c) * n + i0 + seg * 4;
            const float4 xv = *(const float4*)&x[gb];
            const float* op = &sT[c * 132 + seg * 4];
            float4 yv;
            yv.x = g * op[0] + xv.x;
            yv.y = g * op[1] + xv.y;
            yv.z = g * op[2] + xv.z;
            yv.w = g * op[3] + xv.w;
            *(float4*)&y[gb] = yv;
        }
    }
}

// ---------------------------------------------------------------------------
extern "C" void kernel_launch(void* const* d_in, const int* in_sizes, int n_in,
                              void* d_out, int out_size, void* d_ws, size_t ws_size,
                              hipStream_t stream) {
    const float* x     = (const float*)d_in[0];
    const float* Wq    = (const float*)d_in[1];
    const float* bq    = (const float*)d_in[2];
    const float* Wk    = (const float*)d_in[3];
    const float* bk    = (const float*)d_in[4];
    const float* Wv    = (const float*)d_in[5];
    const float* bv    = (const float*)d_in[6];
    const float* gamma = (const float*)d_in[7];
    float* y = (float*)d_out;

    const int N = 64 * 64;
    const int B = in_sizes[0] / (CH * N);   // = 4

    // ws: xT 8.4M | qF 1.05M | kF 1.05M | v2 8.4M | Wcat 0.33M | mKey 64K  ~19.3 MB
    char* ws = (char*)d_ws;
    unsigned char* xT   = (unsigned char*)ws;  ws += (size_t)B * N * CH;
    unsigned char* qF   = (unsigned char*)ws;  ws += (size_t)B * N * RED;
    unsigned char* kF   = (unsigned char*)ws;  ws += (size_t)B * N * RED;
    unsigned char* v2   = (unsigned char*)ws;  ws += (size_t)B * CH * N;
    unsigned char* Wcat = (unsigned char*)ws;  ws += (size_t)640 * CH;
    unsigned* mKey      = (unsigned*)ws;

    hipMemsetAsync(mKey, 0, (size_t)B * N * 4, stream);

    prep_w<<<dim3(640), 128, 0, stream>>>(Wq, Wk, Wv, Wcat);
    cast_xt<<<dim3(N / 64, CH / 64, B), 256, 0, stream>>>(x, xT, N);
    qkv_gemm<<<dim3(N / 128, 5, B), 256, 0, stream>>>(xT, Wcat, bq, bk, bv, qF, kF, v2, N);
    rowmax<<<dim3(N / 128, N / 128, B), 256, 0, stream>>>(qF, kF, mKey, N);
    attn<<<dim3(4 * B, N / 128), 1024, 0, stream>>>(qF, kF, v2, mKey, x, gamma, y, N);
}

// Round 7
// 250.997 us; speedup vs baseline: 1.2151x; 1.2151x over previous
//
#include <hip/hip_runtime.h>
#include <math.h>

#define CH 512
#define RED 64

typedef __attribute__((ext_vector_type(4))) float f32x4;
typedef long i64;

typedef const __attribute__((address_space(1))) void* gas_t;
typedef __attribute__((address_space(3))) void* las_t;

static __device__ __forceinline__ void gl16(const void* g, void* l) {
    __builtin_amdgcn_global_load_lds((gas_t)g, (las_t)l, 16, 0, 0);
}

// pack f32 -> fp8 e4m3
static __device__ __forceinline__ unsigned pk4(float a, float b, float c, float d) {
    int w = __builtin_amdgcn_cvt_pk_fp8_f32(a, b, 0, false);
    w = __builtin_amdgcn_cvt_pk_fp8_f32(c, d, w, true);
    return (unsigned)w;
}
static __device__ __forceinline__ unsigned char pk1(float a) {
    return (unsigned char)(__builtin_amdgcn_cvt_pk_fp8_f32(a, a, 0, false) & 0xFF);
}

// ---------------------------------------------------------------------------
// prep_w: Wq|Wk|Wv f32 -> Wcat fp8 [640][512]; rows 0-63 q, 64-127 k, 128-639 v.
// ---------------------------------------------------------------------------
__global__ __launch_bounds__(128) void prep_w(
    const float* __restrict__ Wq, const float* __restrict__ Wk,
    const float* __restrict__ Wv, unsigned char* __restrict__ Wcat)
{
    const int r = blockIdx.x, t = threadIdx.x;
    const float* src = (r < 64) ? (Wq + (size_t)r * CH)
                     : (r < 128) ? (Wk + (size_t)(r - 64) * CH)
                                 : (Wv + (size_t)(r - 128) * CH);
    const float4 v = *(const float4*)&src[t * 4];
    *(unsigned*)&Wcat[(size_t)r * CH + t * 4] = pk4(v.x, v.y, v.z, v.w);
}

// ---------------------------------------------------------------------------
// cast_xt: x f32 [b][c][n] -> xT fp8 [b][n][512].  64x64 tiles.
// ---------------------------------------------------------------------------
__global__ __launch_bounds__(256) void cast_xt(
    const float* __restrict__ x, unsigned char* __restrict__ xT, int n)
{
    __shared__ float sX[64][65];
    const int b = blockIdx.z, i0 = blockIdx.x * 64, c0 = blockIdx.y * 64;
    const int t = threadIdx.x;
    #pragma unroll
    for (int s = 0; s < 4; ++s) {
        const int id = s * 256 + t, c = id >> 4, seg = id & 15;
        *(float4*)&sX[c][seg * 4] = *(const float4*)&x[((size_t)b * CH + c0 + c) * n + i0 + seg * 4];
    }
    __syncthreads();
    const int i = t >> 2, cp = t & 3;
    uint4 w;
    w.x = pk4(sX[cp*16+ 0][i], sX[cp*16+ 1][i], sX[cp*16+ 2][i], sX[cp*16+ 3][i]);
    w.y = pk4(sX[cp*16+ 4][i], sX[cp*16+ 5][i], sX[cp*16+ 6][i], sX[cp*16+ 7][i]);
    w.z = pk4(sX[cp*16+ 8][i], sX[cp*16+ 9][i], sX[cp*16+10][i], sX[cp*16+11][i]);
    w.w = pk4(sX[cp*16+12][i], sX[cp*16+13][i], sX[cp*16+14][i], sX[cp*16+15][i]);
    *(uint4*)&xT[((size_t)b * n + i0 + i) * CH + c0 + cp * 16] = w;
}

// ---------------------------------------------------------------------------
// qkv_gemm (fp8): out = xT * Wcat^T + bias.  128i x 128o tiles, K=512.
// (proven in R6)
// ---------------------------------------------------------------------------
__global__ __launch_bounds__(256, 4) void qkv_gemm(
    const unsigned char* __restrict__ xT, const unsigned char* __restrict__ Wcat,
    const float* __restrict__ bq, const float* __restrict__ bk,
    const float* __restrict__ bv,
    unsigned char* __restrict__ qF, unsigned char* __restrict__ kF,
    unsigned char* __restrict__ v2, int n)
{
    __shared__ char smem[20480];   // sA 128x80 | sB 128x80
    const int b = blockIdx.z, i0 = blockIdx.x * 128, o0 = blockIdx.y * 128;
    const int t = threadIdx.x, lane = t & 63;
    const int quad = lane >> 4, l16 = lane & 15;
    const int wrow = (t >> 6) & 1, wcol = t >> 7;

    f32x4 acc[4][4];
    const f32x4 zz = {0.f, 0.f, 0.f, 0.f};
    #pragma unroll
    for (int mi = 0; mi < 4; ++mi)
        #pragma unroll
        for (int ci = 0; ci < 4; ++ci) acc[mi][ci] = zz;

    const unsigned char* Ab = xT + ((size_t)b * n + i0) * CH;
    const unsigned char* Bb = Wcat + (size_t)o0 * CH;

    for (int c0 = 0; c0 < CH; c0 += 64) {
        #pragma unroll
        for (int s = 0; s < 5; ++s) {
            const int c = s * 256 + t;
            const bool isA = c < 640;
            const int tc = isA ? c : c - 640;
            const int r = tc / 5, p = (tc % 5) & 3;
            gl16((isA ? Ab : Bb) + (size_t)r * CH + c0 + p * 16,
                 smem + (isA ? 0 : 10240) + (size_t)tc * 16);
        }
        __syncthreads();
        #pragma unroll
        for (int kk = 0; kk < 64; kk += 32) {
            i64 af[4], bf[4];
            #pragma unroll
            for (int mi = 0; mi < 4; ++mi)
                af[mi] = *(const i64*)(smem + (wrow * 64 + mi * 16 + l16) * 80 + kk + quad * 8);
            #pragma unroll
            for (int ci = 0; ci < 4; ++ci)
                bf[ci] = *(const i64*)(smem + 10240 + (wcol * 64 + ci * 16 + l16) * 80 + kk + quad * 8);
            #pragma unroll
            for (int mi = 0; mi < 4; ++mi)
                #pragma unroll
                for (int ci = 0; ci < 4; ++ci)
                    acc[mi][ci] = __builtin_amdgcn_mfma_f32_16x16x32_fp8_fp8(af[mi], bf[ci], acc[mi][ci], 0, 0, 0);
        }
        __syncthreads();
    }

    float bb[4];
    #pragma unroll
    for (int ci = 0; ci < 4; ++ci) {
        const int o = wcol * 64 + ci * 16 + l16;
        bb[ci] = (o0 == 0) ? ((o < 64) ? bq[o] : bk[o - 64]) : bv[o0 - 128 + o];
    }
    __syncthreads();
    unsigned char* sE = (unsigned char*)smem;    // 128 x 144
    if (o0 == 0) {
        #pragma unroll
        for (int mi = 0; mi < 4; ++mi)
            #pragma unroll
            for (int ci = 0; ci < 4; ++ci)
                #pragma unroll
                for (int r = 0; r < 4; ++r)
                    sE[(wrow*64 + mi*16 + quad*4 + r) * 144 + wcol*64 + ci*16 + l16] =
                        pk1(acc[mi][ci][r] + bb[ci]);
    } else {
        #pragma unroll
        for (int mi = 0; mi < 4; ++mi)
            #pragma unroll
            for (int ci = 0; ci < 4; ++ci)
                #pragma unroll
                for (int r = 0; r < 4; ++r)
                    sE[(wcol*64 + ci*16 + l16) * 144 + wrow*64 + mi*16 + quad*4 + r] =
                        pk1(acc[mi][ci][r] + bb[ci]);
    }
    __syncthreads();
    if (o0 == 0) {
        #pragma unroll
        for (int u = 0; u < 2; ++u) {
            const int id = u * 256 + t, i = id >> 2, p = id & 3;
            *(uint4*)&qF[((size_t)b * n + i0 + i) * RED + p * 16] = *(const uint4*)&sE[i * 144 + p * 16];
        }
        #pragma unroll
        for (int u = 0; u < 2; ++u) {
            const int id = u * 256 + t, i = id >> 2, p = id & 3;
            *(uint4*)&kF[((size_t)b * n + i0 + i) * RED + p * 16] = *(const uint4*)&sE[i * 144 + 64 + p * 16];
        }
    } else {
        #pragma unroll
        for (int u = 0; u < 4; ++u) {
            const int id = u * 256 + t, o = id >> 3, p = id & 7;
            *(uint4*)&v2[((size_t)b * CH + (o0 - 128) + o) * n + i0 + p * 16] =
                *(const uint4*)&sE[o * 144 + p * 16];
        }
    }
}

// ---------------------------------------------------------------------------
// rowmax: m_i = max_j S (bit-identical S to attn's fp8 MFMA).  (proven in R6)
// ---------------------------------------------------------------------------
__global__ __launch_bounds__(256, 4) void rowmax(
    const unsigned char* __restrict__ qF, const unsigned char* __restrict__ kF,
    unsigned* __restrict__ mKey, int n)
{
    __shared__ char smem[20480];
    const int b = blockIdx.z, i0 = blockIdx.y * 128, j0 = blockIdx.x * 128;
    const int t = threadIdx.x, lane = t & 63;
    const int quad = lane >> 4, l16 = lane & 15;
    const int wrow = (t >> 6) & 1, wcol = t >> 7;

    const unsigned char* Qb = qF + ((size_t)b * n + i0) * RED;
    const unsigned char* Kb = kF + ((size_t)b * n + j0) * RED;
    #pragma unroll
    for (int s = 0; s < 5; ++s) {
        const int c = s * 256 + t;
        const bool isQ = c < 640;
        const int tc = isQ ? c : c - 640;
        const int r = tc / 5, p = (tc % 5) & 3;
        gl16((isQ ? Qb : Kb) + (size_t)r * RED + p * 16,
             smem + (isQ ? 0 : 10240) + (size_t)tc * 16);
    }
    __syncthreads();

    f32x4 acc[4][4];
    const f32x4 zz = {0.f, 0.f, 0.f, 0.f};
    #pragma unroll
    for (int mi = 0; mi < 4; ++mi)
        #pragma unroll
        for (int ci = 0; ci < 4; ++ci) acc[mi][ci] = zz;

    #pragma unroll
    for (int kk = 0; kk < 64; kk += 32) {
        i64 af[4], bf[4];
        #pragma unroll
        for (int mi = 0; mi < 4; ++mi)
            af[mi] = *(const i64*)(smem + (wrow * 64 + mi * 16 + l16) * 80 + kk + quad * 8);
        #pragma unroll
        for (int ci = 0; ci < 4; ++ci)
            bf[ci] = *(const i64*)(smem + 10240 + (wcol * 64 + ci * 16 + l16) * 80 + kk + quad * 8);
        #pragma unroll
        for (int mi = 0; mi < 4; ++mi)
            #pragma unroll
            for (int ci = 0; ci < 4; ++ci)
                acc[mi][ci] = __builtin_amdgcn_mfma_f32_16x16x32_fp8_fp8(af[mi], bf[ci], acc[mi][ci], 0, 0, 0);
    }

    #pragma unroll
    for (int mi = 0; mi < 4; ++mi)
        #pragma unroll
        for (int r = 0; r < 4; ++r) {
            float mx = fmaxf(fmaxf(acc[mi][0][r], acc[mi][1][r]),
                             fmaxf(acc[mi][2][r], acc[mi][3][r]));
            #pragma unroll
            for (int off = 1; off < 16; off <<= 1) mx = fmaxf(mx, __shfl_xor(mx, off));
            if (l16 == 0) {
                union { float f; unsigned u; } cv; cv.f = mx;
                const unsigned key = ((int)cv.u >= 0) ? (cv.u + 0x80000000u) : ~cv.u;
                atomicMax(&mKey[(size_t)b * n + i0 + wrow * 64 + mi * 16 + quad * 4 + r], key);
            }
        }
}

// ---------------------------------------------------------------------------
// attn v2: 128q x 128ch per block, 512 thr (8 waves), wave tile = 4(q) x 2(ch).
// S^T = K.Q^T (Q in registers) -> P packed-b32 row writes -> PV reads P as
// B-operand directly (no transpose trip).  Stride-64 LDS + XOR swizzle
// (part ^= (row>>1)&3) -> 2-way max on all fragment traffic.  K/V double-
// buffered: stage of chunk c+1 issued before compute of chunk c.
// LDS 34 KB, __launch_bounds__(512,4) -> 2 blocks/CU, 128 VGPR budget.
// ---------------------------------------------------------------------------
#define STGSZ 12288
#define SPOFF 24576
#define SLOFF 32768

__global__ __launch_bounds__(512, 4) void attn(
    const unsigned char* __restrict__ qF,   // [b][n][64] fp8
    const unsigned char* __restrict__ kF,   // [b][n][64] fp8
    const unsigned char* __restrict__ v2,   // [b][512][n] fp8
    const unsigned* __restrict__ mKey,
    const float* __restrict__ x, const float* __restrict__ gamma,
    float* __restrict__ y, int n)
{
    __shared__ char smem[34816];
    const int combo = blockIdx.x, it = blockIdx.y;
    const int b = combo >> 2, ch0 = (combo & 3) * 128;
    const int i0 = it * 128;
    const int t = threadIdx.x, lane = t & 63, w = t >> 6;
    const int quad = lane >> 4, l16 = lane & 15;
    const int qh = w & 1, g = w >> 1;
    const int sw = (l16 >> 1) & 3;          // read-side swizzle key
    const int boff = (quad & 1) * 8;        // byte-in-part for fragments
    const int phalf = quad >> 1;            // part contribution from quad

    const unsigned char* Qb = qF + ((size_t)b * n + i0) * RED;
    const unsigned char* Kb = kF + (size_t)b * n * RED;
    const unsigned char* Vb = v2 + ((size_t)b * CH + ch0) * n;

    // ---- initial staging: Q (into sP region) + chunk 0 K/V (into buf0)
    {
        const int r = t >> 2, s = t & 3, gs = s ^ ((r >> 1) & 3);
        gl16(Qb + (size_t)r * RED + gs * 16, smem + SPOFF + (size_t)t * 16);
        if (t < 256) {
            const int kr = t >> 2, ks = t & 3, kgs = ks ^ ((kr >> 1) & 3);
            gl16(Kb + (size_t)kr * RED + kgs * 16, smem + (size_t)t * 16);
        }
        gl16(Vb + (size_t)r * n + gs * 16, smem + 4096 + (size_t)t * 16);
    }
    __syncthreads();   // drains all staging (vmcnt 0 at barrier)

    // ---- preload Q fragments (B-operand layout: lane=q-col, bytes=red)
    i64 qreg[4][2];
    #pragma unroll
    for (int qt = 0; qt < 4; ++qt) {
        const int row = qh * 64 + qt * 16 + l16;
        #pragma unroll
        for (int kki = 0; kki < 2; ++kki) {
            const int p = (kki * 2 + phalf) ^ sw;
            qreg[qt][kki] = *(const i64*)(smem + SPOFF + row * 64 + p * 16 + boff);
        }
    }
    float mrow[4];
    #pragma unroll
    for (int qt = 0; qt < 4; ++qt) {
        const unsigned u = mKey[(size_t)b * n + i0 + qh * 64 + qt * 16 + l16];
        const unsigned bits = (u >= 0x80000000u) ? (u - 0x80000000u) : ~u;
        union { unsigned u; float f; } cv; cv.u = bits;
        mrow[qt] = cv.f;
    }

    f32x4 acc[4][2];
    const f32x4 zz = {0.f, 0.f, 0.f, 0.f};
    #pragma unroll
    for (int qt = 0; qt < 4; ++qt) { acc[qt][0] = zz; acc[qt][1] = zz; }
    float lacc[4] = {0.f, 0.f, 0.f, 0.f};

    const int nchunks = n >> 6;
    for (int c = 0; c < nchunks; ++c) {
        const int j0 = c << 6;
        char* cur = smem + (c & 1) * STGSZ;
        char* nxt = smem + ((c & 1) ^ 1) * STGSZ;

        __syncthreads();   // B1: prior PV reads + Q-frag reads done; P region free
        if (j0 + 64 < n) {  // stage next chunk (drains at B2 -> latency hidden by S phase)
            const int jn = j0 + 64;
            const int r = t >> 2, s = t & 3, gs = s ^ ((r >> 1) & 3);
            if (t < 256)
                gl16(Kb + (size_t)(jn + r) * RED + gs * 16, nxt + (size_t)t * 16);
            gl16(Vb + (size_t)r * n + jn + gs * 16, nxt + 4096 + (size_t)t * 16);
        }

        // ---- S^T = K.Q^T : wave (qh,g) -> j-tile g, q-tiles qh*4..+3
        f32x4 S[4];
        #pragma unroll
        for (int qt = 0; qt < 4; ++qt) S[qt] = zz;
        #pragma unroll
        for (int kki = 0; kki < 2; ++kki) {
            const int p = (kki * 2 + phalf) ^ sw;
            const i64 kf = *(const i64*)(cur + (g * 16 + l16) * 64 + p * 16 + boff);
            #pragma unroll
            for (int qt = 0; qt < 4; ++qt)
                S[qt] = __builtin_amdgcn_mfma_f32_16x16x32_fp8_fp8(kf, qreg[qt][kki], S[qt], 0, 0, 0);
        }
        // ---- P = exp(S - m): lane holds q-col l16, j-rows quad*4+r -> packed b32
        #pragma unroll
        for (int qt = 0; qt < 4; ++qt) {
            const float e0 = __expf(S[qt][0] - mrow[qt]);
            const float e1 = __expf(S[qt][1] - mrow[qt]);
            const float e2 = __expf(S[qt][2] - mrow[qt]);
            const float e3 = __expf(S[qt][3] - mrow[qt]);
            lacc[qt] += (e0 + e1) + (e2 + e3);
            const int qrow = qh * 64 + qt * 16 + l16;
            const int pp = g ^ sw;
            *(unsigned*)(smem + SPOFF + qrow * 64 + pp * 16 + quad * 4) = pk4(e0, e1, e2, e3);
        }
        __syncthreads();   // B2: P visible; next-chunk staging drained

        // ---- PV: O^T tiles, A = V rows (c), B = P rows (q)
        #pragma unroll
        for (int kki = 0; kki < 2; ++kki) {
            const int p = (kki * 2 + phalf) ^ sw;
            i64 vf[2], pf[4];
            #pragma unroll
            for (int ct = 0; ct < 2; ++ct) {
                const int row = (g * 2 + ct) * 16 + l16;
                vf[ct] = *(const i64*)(cur + 4096 + row * 64 + p * 16 + boff);
            }
            #pragma unroll
            for (int qt = 0; qt < 4; ++qt) {
                const int qrow = qh * 64 + qt * 16 + l16;
                pf[qt] = *(const i64*)(smem + SPOFF + qrow * 64 + p * 16 + boff);
            }
            #pragma unroll
            for (int qt = 0; qt < 4; ++qt)
                #pragma unroll
                for (int ct = 0; ct < 2; ++ct)
                    acc[qt][ct] = __builtin_amdgcn_mfma_f32_16x16x32_fp8_fp8(vf[ct], pf[qt], acc[qt][ct], 0, 0, 0);
        }
    }

    // ---- l reduction: over quads (shfl), then over the 4 g-waves (LDS)
    float* sL = (float*)(smem + SLOFF);   // [8 waves][64]
    #pragma unroll
    for (int qt = 0; qt < 4; ++qt) {
        float v = lacc[qt];
        v += __shfl_xor(v, 16);
        v += __shfl_xor(v, 32);
        lacc[qt] = v;
    }
    if (quad == 0) {
        #pragma unroll
        for (int qt = 0; qt < 4; ++qt) sL[w * 64 + qt * 16 + l16] = lacc[qt];
    }
    __syncthreads();
    float il[4];
    #pragma unroll
    for (int qt = 0; qt < 4; ++qt) {
        const int idx = qt * 16 + l16;
        il[qt] = 1.0f / (sL[qh * 64 + idx] + sL[(2 + qh) * 64 + idx] +
                         sL[(4 + qh) * 64 + idx] + sL[(6 + qh) * 64 + idx]);
    }

    // ---- epilogue: 4 rounds of 32 channels; transpose via LDS, y = g*(O/l)+x
    const float gm = gamma[0];
    float* sT = (float*)smem;   // [32][132] f32 = 16.9 KB (aliases staging)
    #pragma unroll
    for (int cr = 0; cr < 4; ++cr) {
        __syncthreads();
        if (g == cr) {
            #pragma unroll
            for (int ct = 0; ct < 2; ++ct)
                #pragma unroll
                for (int qt = 0; qt < 4; ++qt)
                    #pragma unroll
                    for (int r = 0; r < 4; ++r)
                        sT[(ct * 16 + quad * 4 + r) * 132 + qh * 64 + qt * 16 + l16] =
                            acc[qt][ct][r] * il[qt];
        }
        __syncthreads();
        const int row = t >> 4, seg = (t & 15) * 8;
        const size_t gb = ((size_t)b * CH + ch0 + cr * 32 + row) * n + i0 + seg;
        #pragma unroll
        for (int u = 0; u < 2; ++u) {
            const float4 xv = *(const float4*)&x[gb + u * 4];
            const float* op = &sT[row * 132 + seg + u * 4];
            float4 yv;
            yv.x = gm * op[0] + xv.x;
            yv.y = gm * op[1] + xv.y;
            yv.z = gm * op[2] + xv.z;
            yv.w = gm * op[3] + xv.w;
            *(float4*)&y[gb + u * 4] = yv;
        }
    }
}

// ---------------------------------------------------------------------------
extern "C" void kernel_launch(void* const* d_in, const int* in_sizes, int n_in,
                              void* d_out, int out_size, void* d_ws, size_t ws_size,
                              hipStream_t stream) {
    const float* x     = (const float*)d_in[0];
    const float* Wq    = (const float*)d_in[1];
    const float* bq    = (const float*)d_in[2];
    const float* Wk    = (const float*)d_in[3];
    const float* bk    = (const float*)d_in[4];
    const float* Wv    = (const float*)d_in[5];
    const float* bv    = (const float*)d_in[6];
    const float* gamma = (const float*)d_in[7];
    float* y = (float*)d_out;

    const int N = 64 * 64;
    const int B = in_sizes[0] / (CH * N);   // = 4

    char* ws = (char*)d_ws;
    unsigned char* xT   = (unsigned char*)ws;  ws += (size_t)B * N * CH;
    unsigned char* qF   = (unsigned char*)ws;  ws += (size_t)B * N * RED;
    unsigned char* kF   = (unsigned char*)ws;  ws += (size_t)B * N * RED;
    unsigned char* v2   = (unsigned char*)ws;  ws += (size_t)B * CH * N;
    unsigned char* Wcat = (unsigned char*)ws;  ws += (size_t)640 * CH;
    unsigned* mKey      = (unsigned*)ws;

    hipMemsetAsync(mKey, 0, (size_t)B * N * 4, stream);

    prep_w<<<dim3(640), 128, 0, stream>>>(Wq, Wk, Wv, Wcat);
    cast_xt<<<dim3(N / 64, CH / 64, B), 256, 0, stream>>>(x, xT, N);
    qkv_gemm<<<dim3(N / 128, 5, B), 256, 0, stream>>>(xT, Wcat, bq, bk, bv, qF, kF, v2, N);
    rowmax<<<dim3(N / 128, N / 128, B), 256, 0, stream>>>(qF, kF, mKey, N);
    attn<<<dim3(4 * B, N / 128), 512, 0, stream>>>(qF, kF, v2, mKey, x, gamma, y, N);
}